// Round 1
// baseline (1682.620 us; speedup 1.0000x reference)
//
#include <hip/hip_runtime.h>
#include <math.h>

// Problem constants
#define L_LAYERS 2
#define DM   128      // D_MODEL
#define DI   256      // D_INNER
#define DS   16       // D_STATE
#define DTR  8        // DT_RANK
#define DFF  256
#define PLEN 16       // patch len
#define BSEQ 32       // bs*nvars
#define TSEQ 1024     // patch num
#define MTOK (BSEQ*TSEQ)   // 32768

#define EPI_NONE 0
#define EPI_BIAS 1
#define EPI_GELU 2
#define EPI_XPROJ 3

__device__ __forceinline__ float silu_f(float x){ return x / (1.f + __expf(-x)); }
__device__ __forceinline__ float gelu_f(float x){ return 0.5f*x*(1.f + erff(x*0.7071067811865475f)); }
__device__ __forceinline__ float softplus_f(float x){ return (x > 20.f) ? x : log1pf(__expf(x)); }

// ---------------------------------------------------------------------------
// Patch embedding: h[bv*1024+n, d] = sum_p x[bv,p,n]*Wp[d,p] + bp[d]
// grid (32 bv, 16 ntiles of 64), block 256
__global__ __launch_bounds__(256) void patch_embed(
    const float* __restrict__ x, const float* __restrict__ Wp,
    const float* __restrict__ bp, float* __restrict__ h)
{
    int bv = blockIdx.x, n0 = blockIdx.y * 64;
    __shared__ float xs[PLEN][64];
    __shared__ float ws[PLEN][DM];
    __shared__ float bs[DM];
    int tid = threadIdx.x;
    {
        int c = tid & 63, r0 = tid >> 6;
        for (int p = r0; p < PLEN; p += 4)
            xs[p][c] = x[bv*(PLEN*TSEQ) + p*TSEQ + n0 + c];
    }
    for (int i = tid; i < DM*PLEN; i += 256) {
        int d = i >> 4, p = i & 15;
        ws[p][d] = Wp[i];
    }
    if (tid < DM) bs[tid] = bp[tid];
    __syncthreads();
    int tm = tid & 15;   // n-group: n = n0 + tm*4 + i
    int tn = tid >> 4;   // d-group: d = tn*8 + j
    float acc[4][8];
#pragma unroll
    for (int i=0;i<4;i++)
#pragma unroll
        for (int j=0;j<8;j++) acc[i][j] = bs[tn*8+j];
#pragma unroll
    for (int p=0;p<PLEN;p++) {
        float4 a = *(const float4*)&xs[p][tm*4];
        float4 w0 = *(const float4*)&ws[p][tn*8];
        float4 w1 = *(const float4*)&ws[p][tn*8+4];
        const float* ap = (const float*)&a;
        const float* wp0 = (const float*)&w0;
        const float* wp1 = (const float*)&w1;
#pragma unroll
        for (int i=0;i<4;i++){
#pragma unroll
            for (int j=0;j<4;j++){
                acc[i][j]   += ap[i]*wp0[j];
                acc[i][j+4] += ap[i]*wp1[j];
            }
        }
    }
#pragma unroll
    for (int i=0;i<4;i++){
        size_t row = (size_t)(bv*TSEQ + n0 + tm*4 + i)*DM + tn*8;
        float4 v0 = make_float4(acc[i][0],acc[i][1],acc[i][2],acc[i][3]);
        float4 v1 = make_float4(acc[i][4],acc[i][5],acc[i][6],acc[i][7]);
        *(float4*)&h[row]   = v0;
        *(float4*)&h[row+4] = v1;
    }
}

// ---------------------------------------------------------------------------
// Generic tiled GEMM: C[M,N] = A[M,K] @ W[N,K]^T (+bias/act)
// BM=BN=64, BK=16, 256 threads, 4x4 per thread.
template<int EPI>
__global__ __launch_bounds__(256) void gemm64(
    const float* __restrict__ A, const float* __restrict__ W,
    const float* __restrict__ bias, float* __restrict__ C,
    int M, int N, int K,
    float* __restrict__ dtR, float* __restrict__ BT, float* __restrict__ CT)
{
    int m0 = blockIdx.x * 64;
    int n0 = blockIdx.y * 64;
    __shared__ float As[16][64];
    __shared__ float Ws[16][64];
    int tid = threadIdx.x;
    int lr = tid >> 2;          // 0..63
    int lk = (tid & 3) * 4;     // 0,4,8,12
    int tm = tid & 15, tn = tid >> 4;
    float acc[4][4] = {{0.f}};
    for (int k0 = 0; k0 < K; k0 += 16) {
        float4 av = *(const float4*)&A[(size_t)(m0+lr)*K + k0 + lk];
        float4 wv = make_float4(0.f,0.f,0.f,0.f);
        if (n0 + lr < N) wv = *(const float4*)&W[(size_t)(n0+lr)*K + k0 + lk];
        As[lk+0][lr]=av.x; As[lk+1][lr]=av.y; As[lk+2][lr]=av.z; As[lk+3][lr]=av.w;
        Ws[lk+0][lr]=wv.x; Ws[lk+1][lr]=wv.y; Ws[lk+2][lr]=wv.z; Ws[lk+3][lr]=wv.w;
        __syncthreads();
#pragma unroll
        for (int k=0;k<16;k++){
            float4 a = *(const float4*)&As[k][tm*4];
            float4 b = *(const float4*)&Ws[k][tn*4];
            acc[0][0]+=a.x*b.x; acc[0][1]+=a.x*b.y; acc[0][2]+=a.x*b.z; acc[0][3]+=a.x*b.w;
            acc[1][0]+=a.y*b.x; acc[1][1]+=a.y*b.y; acc[1][2]+=a.y*b.z; acc[1][3]+=a.y*b.w;
            acc[2][0]+=a.z*b.x; acc[2][1]+=a.z*b.y; acc[2][2]+=a.z*b.z; acc[2][3]+=a.z*b.w;
            acc[3][0]+=a.w*b.x; acc[3][1]+=a.w*b.y; acc[3][2]+=a.w*b.z; acc[3][3]+=a.w*b.w;
        }
        __syncthreads();
    }
    if (EPI == EPI_XPROJ) {
#pragma unroll
        for (int i=0;i<4;i++){
            int m = m0 + tm*4 + i; int bb = m >> 10, t = m & 1023;
#pragma unroll
            for (int j=0;j<4;j++){
                int n = n0 + tn*4 + j;
                if (n < N) {
                    float v = acc[i][j];
                    if (n < DTR)          dtR[(size_t)m*DTR + n] = v;
                    else if (n < DTR+DS)  BT[(size_t)(bb*DS + n-DTR)*TSEQ + t] = v;
                    else                  CT[(size_t)(bb*DS + n-DTR-DS)*TSEQ + t] = v;
                }
            }
        }
    } else {
#pragma unroll
        for (int i=0;i<4;i++){
            int m = m0 + tm*4 + i;
            float4 v = make_float4(acc[i][0],acc[i][1],acc[i][2],acc[i][3]);
            if (EPI == EPI_BIAS || EPI == EPI_GELU) {
                int n = n0 + tn*4;
                v.x += bias[n]; v.y += bias[n+1]; v.z += bias[n+2]; v.w += bias[n+3];
            }
            if (EPI == EPI_GELU) {
                v.x = gelu_f(v.x); v.y = gelu_f(v.y); v.z = gelu_f(v.z); v.w = gelu_f(v.w);
            }
            *(float4*)&C[(size_t)m*N + n0 + tn*4] = v;
        }
    }
}

// ---------------------------------------------------------------------------
// Causal depthwise conv (width 4) + bias + SiLU, dual-layout output.
// grid (32 b, 4 ctiles, 16 ttiles), block 256
__global__ __launch_bounds__(256) void conv_silu(
    const float* __restrict__ xz, const float* __restrict__ cw,
    const float* __restrict__ cb, float* __restrict__ xcR, float* __restrict__ xcT)
{
    int b = blockIdx.x, c0 = blockIdx.y*64, t0 = blockIdx.z*64;
    __shared__ float xin_s[67][64];
    __shared__ float out_s[64][65];
    __shared__ float cws[64][5];
    __shared__ float cbs[64];
    int tid = threadIdx.x;
    if (tid < 256) { int c = tid >> 2, k = tid & 3; cws[c][k] = cw[(c0+c)*4 + k]; }
    if (tid < 64) cbs[tid] = cb[c0+tid];
    {
        int c = tid & 63, r0 = tid >> 6;
        for (int r = r0; r < 67; r += 4) {
            int t = t0 - 3 + r;
            xin_s[r][c] = (t >= 0) ? xz[(size_t)(b*TSEQ + t)*(2*DI) + c0 + c] : 0.f;
        }
    }
    __syncthreads();
#pragma unroll
    for (int p = 0; p < 16; p++) {
        int idx = p*256 + tid;
        int tl = idx >> 6, cl = idx & 63;
        float v = cbs[cl];
#pragma unroll
        for (int k=0;k<4;k++) v += cws[cl][k]*xin_s[tl+k][cl];
        v = silu_f(v);
        out_s[tl][cl] = v;
        xcR[(size_t)(b*TSEQ + t0 + tl)*DI + c0 + cl] = v;
    }
    __syncthreads();
#pragma unroll
    for (int p = 0; p < 16; p++) {
        int idx = p*256 + tid;
        int cl = idx >> 6, tl = idx & 63;
        xcT[(size_t)(b*DI + c0 + cl)*TSEQ + t0 + tl] = out_s[tl][cl];
    }
}

// ---------------------------------------------------------------------------
// delta = softplus(dt @ dtw^T + dtb), written transposed: deltaT[b,d,t]
// grid (512 mtiles of 64 tokens, 4 dtiles of 64), block 256
__global__ __launch_bounds__(256) void dtproj_softplus(
    const float* __restrict__ dtR, const float* __restrict__ dtw,
    const float* __restrict__ dtb, float* __restrict__ deltaT)
{
    int m0 = blockIdx.x*64, d0 = blockIdx.y*64;
    __shared__ float dts[DTR][64];
    __shared__ float wts[DTR][64];
    __shared__ float bsh[64];
    int tid = threadIdx.x;
    for (int i = tid; i < 512; i += 256) {
        int j = i >> 6, r = i & 63;
        dts[j][r] = dtR[(size_t)(m0+r)*DTR + j];
    }
    for (int i = tid; i < 512; i += 256) {
        int j = i >> 6, d = i & 63;
        wts[j][d] = dtw[(size_t)(d0+d)*DTR + j];
    }
    if (tid < 64) bsh[tid] = dtb[d0+tid];
    __syncthreads();
    int tm = tid & 15, tn = tid >> 4;
    float acc[4][4];
#pragma unroll
    for (int i=0;i<4;i++)
#pragma unroll
        for (int j=0;j<4;j++) acc[i][j] = bsh[tn*4+j];
#pragma unroll
    for (int k=0;k<DTR;k++){
        float4 a = *(const float4*)&dts[k][tm*4];
        float4 w = *(const float4*)&wts[k][tn*4];
        acc[0][0]+=a.x*w.x; acc[0][1]+=a.x*w.y; acc[0][2]+=a.x*w.z; acc[0][3]+=a.x*w.w;
        acc[1][0]+=a.y*w.x; acc[1][1]+=a.y*w.y; acc[1][2]+=a.y*w.z; acc[1][3]+=a.y*w.w;
        acc[2][0]+=a.z*w.x; acc[2][1]+=a.z*w.y; acc[2][2]+=a.z*w.z; acc[2][3]+=a.z*w.w;
        acc[3][0]+=a.w*w.x; acc[3][1]+=a.w*w.y; acc[3][2]+=a.w*w.z; acc[3][3]+=a.w*w.w;
    }
    int bb = m0 >> 10;
    int tl = (m0 & 1023) + tm*4;
#pragma unroll
    for (int j=0;j<4;j++){
        float4 v = make_float4(softplus_f(acc[0][j]), softplus_f(acc[1][j]),
                               softplus_f(acc[2][j]), softplus_f(acc[3][j]));
        *(float4*)&deltaT[(size_t)(bb*DI + d0 + tn*4 + j)*TSEQ + tl] = v;
    }
}

// ---------------------------------------------------------------------------
// Selective scan. thread = (b, d, s). grid 512 blocks x 256 (16 d x 16 s).
// Fuses y = (scan + u*D) * silu(z); writes y row-major for out_proj GEMM.
__global__ __launch_bounds__(256) void scan_kernel(
    const float* __restrict__ deltaT, const float* __restrict__ xcT,
    const float* __restrict__ BT, const float* __restrict__ CT,
    const float* __restrict__ xz, const float* __restrict__ Alog,
    const float* __restrict__ Dp, float* __restrict__ yR)
{
    int blk = blockIdx.x;
    int b = blk >> 4, dg = blk & 15;
    int tid = threadIdx.x;
    int s = tid & 15, d = dg*16 + (tid >> 4);
    float A = -__expf(Alog[d*DS + s]);
    float Dd = Dp[d];
    const float* dptr = deltaT + (size_t)(b*DI + d)*TSEQ;
    const float* uptr = xcT   + (size_t)(b*DI + d)*TSEQ;
    const float* bptr = BT    + (size_t)(b*DS + s)*TSEQ;
    const float* cptr = CT    + (size_t)(b*DS + s)*TSEQ;
    float h = 0.f;
    for (int t0 = 0; t0 < TSEQ; t0 += 4) {
        float4 dl4 = *(const float4*)(dptr + t0);
        float4 uu4 = *(const float4*)(uptr + t0);
        float4 Bv4 = *(const float4*)(bptr + t0);
        float4 Cv4 = *(const float4*)(cptr + t0);
        const float* dl = (const float*)&dl4;
        const float* uu = (const float*)&uu4;
        const float* Bv = (const float*)&Bv4;
        const float* Cv = (const float*)&Cv4;
#pragma unroll
        for (int j=0;j<4;j++){
            float dlt = dl[j];
            float dA = __expf(dlt*A);
            h = dA*h + (dlt*uu[j])*Bv[j];
            float yp = h*Cv[j];
            yp += __shfl_xor(yp, 1, 64);
            yp += __shfl_xor(yp, 2, 64);
            yp += __shfl_xor(yp, 4, 64);
            yp += __shfl_xor(yp, 8, 64);
            if (s == 0) {
                int t = t0 + j;
                float z = xz[(size_t)(b*TSEQ + t)*(2*DI) + DI + d];
                float y = (yp + uu[j]*Dd) * silu_f(z);
                yR[(size_t)(b*TSEQ + t)*DI + d] = y;
            }
        }
    }
}

// ---------------------------------------------------------------------------
// Final transpose: out[bv, d, n] = h[bv*1024+n, d]
// grid (32 ntiles, 4 dtiles, 32 bv), block 256
__global__ __launch_bounds__(256) void final_transpose(
    const float* __restrict__ h, float* __restrict__ out)
{
    int n0 = blockIdx.x*32, d0 = blockIdx.y*32, bv = blockIdx.z;
    __shared__ float ts[32][33];
    int tid = threadIdx.x;
    int c = tid & 31, r0 = tid >> 5;
    for (int r = r0; r < 32; r += 8)
        ts[r][c] = h[(size_t)(bv*TSEQ + n0 + r)*DM + d0 + c];
    __syncthreads();
    for (int r = r0; r < 32; r += 8)
        out[(size_t)(bv*DM + d0 + r)*TSEQ + n0 + c] = ts[c][r];
}

// ---------------------------------------------------------------------------
extern "C" void kernel_launch(void* const* d_in, const int* in_sizes, int n_in,
                              void* d_out, int out_size, void* d_ws, size_t ws_size,
                              hipStream_t stream)
{
    const float* x     = (const float*)d_in[0];
    const float* Wp    = (const float*)d_in[1];
    const float* Wpb   = (const float*)d_in[2];
    const float* inW   = (const float*)d_in[3];
    const float* convW = (const float*)d_in[4];
    const float* convB = (const float*)d_in[5];
    const float* xpW   = (const float*)d_in[6];
    const float* dtW   = (const float*)d_in[7];
    const float* dtB   = (const float*)d_in[8];
    const float* Alog  = (const float*)d_in[9];
    const float* Dp    = (const float*)d_in[10];
    const float* outW  = (const float*)d_in[11];
    const float* l1W   = (const float*)d_in[12];
    const float* l1B   = (const float*)d_in[13];
    const float* l2W   = (const float*)d_in[14];
    const float* l2B   = (const float*)d_in[15];
    float* out = (float*)d_out;

    float* ws = (float*)d_ws;
    float* h    = ws;                       // 32768*128
    float* xz   = h    + (size_t)MTOK*DM;   // 32768*512
    float* xcR  = xz   + (size_t)MTOK*2*DI; // 32768*256
    float* xcT  = xcR  + (size_t)MTOK*DI;   // 32768*256
    float* dtRb = xcT  + (size_t)MTOK*DI;   // 32768*8
    float* BTb  = dtRb + (size_t)MTOK*DTR;  // 32*16*1024
    float* CTb  = BTb  + (size_t)BSEQ*DS*TSEQ;
    float* dltT = CTb  + (size_t)BSEQ*DS*TSEQ; // 32768*256
    float* yR   = xcR;   // alias: xcR dead after x_proj GEMM
    float* ffn  = xz;    // alias: xz dead after scan (z consumed)

    patch_embed<<<dim3(32,16), 256, 0, stream>>>(x, Wp, Wpb, h);

    for (int L = 0; L < L_LAYERS; L++) {
        const float* inW_l   = inW   + (size_t)L*2*DI*DM;
        const float* convW_l = convW + (size_t)L*DI*4;
        const float* convB_l = convB + (size_t)L*DI;
        const float* xpW_l   = xpW   + (size_t)L*(DTR+2*DS)*DI;
        const float* dtW_l   = dtW   + (size_t)L*DI*DTR;
        const float* dtB_l   = dtB   + (size_t)L*DI;
        const float* Alog_l  = Alog  + (size_t)L*DI*DS;
        const float* Dp_l    = Dp    + (size_t)L*DI;
        const float* outW_l  = outW  + (size_t)L*DM*DI;
        const float* l1W_l   = l1W   + (size_t)L*DFF*DM;
        const float* l1B_l   = l1B   + (size_t)L*DFF;
        const float* l2W_l   = l2W   + (size_t)L*DM*DFF;
        const float* l2B_l   = l2B   + (size_t)L*DM;

        // xz = h @ in_w^T : (32768 x 512), K=128
        gemm64<EPI_NONE><<<dim3(MTOK/64, (2*DI)/64), 256, 0, stream>>>(
            h, inW_l, nullptr, xz, MTOK, 2*DI, DM, nullptr, nullptr, nullptr);
        // conv + silu
        conv_silu<<<dim3(BSEQ, DI/64, TSEQ/64), 256, 0, stream>>>(
            xz, convW_l, convB_l, xcR, xcT);
        // x_dbl = xc @ xp_w^T : (32768 x 40), K=256, scatter epilogue
        gemm64<EPI_XPROJ><<<dim3(MTOK/64, 1), 256, 0, stream>>>(
            xcR, xpW_l, nullptr, nullptr, MTOK, DTR+2*DS, DI, dtRb, BTb, CTb);
        // delta = softplus(dt @ dtp_w^T + b), transposed out
        dtproj_softplus<<<dim3(MTOK/64, DI/64), 256, 0, stream>>>(
            dtRb, dtW_l, dtB_l, dltT);
        // selective scan (+ u*D + silu(z) gate)
        scan_kernel<<<dim3(BSEQ*(DI/16)), 256, 0, stream>>>(
            dltT, xcT, BTb, CTb, xz, Alog_l, Dp_l, yR);
        // h = y @ out_w^T : (32768 x 128), K=256
        gemm64<EPI_NONE><<<dim3(MTOK/64, DM/64), 256, 0, stream>>>(
            yR, outW_l, nullptr, h, MTOK, DM, DI, nullptr, nullptr, nullptr);
        // ffn = gelu(h @ l1^T + b1) : (32768 x 256), K=128
        gemm64<EPI_GELU><<<dim3(MTOK/64, DFF/64), 256, 0, stream>>>(
            h, l1W_l, l1B_l, ffn, MTOK, DFF, DM, nullptr, nullptr, nullptr);
        // h = ffn @ l2^T + b2 : (32768 x 128), K=256
        gemm64<EPI_BIAS><<<dim3(MTOK/64, DM/64), 256, 0, stream>>>(
            ffn, l2W_l, l2B_l, h, MTOK, DM, DFF, nullptr, nullptr, nullptr);
    }

    final_transpose<<<dim3(TSEQ/32, DM/32, BSEQ), 256, 0, stream>>>(h, out);
}

// Round 2
// 821.507 us; speedup vs baseline: 2.0482x; 2.0482x over previous
//
#include <hip/hip_runtime.h>
#include <math.h>

// Problem constants
#define L_LAYERS 2
#define DM   128      // D_MODEL
#define DI   256      // D_INNER
#define DS   16       // D_STATE
#define DTR  8        // DT_RANK
#define DFF  256
#define PLEN 16       // patch len
#define BSEQ 32       // bs*nvars
#define TSEQ 1024     // patch num
#define MTOK (BSEQ*TSEQ)   // 32768
#define NCH  16       // scan chunks
#define CSZ  64       // TSEQ/NCH
#define XDW  40       // x_dbl width = DTR + 2*DS

#define EPI_NONE 0
#define EPI_BIAS 1
#define EPI_GELU 2
#define EPI_XDBL 3

__device__ __forceinline__ float silu_f(float x){ return x / (1.f + __expf(-x)); }
__device__ __forceinline__ float gelu_f(float x){ return 0.5f*x*(1.f + erff(x*0.7071067811865475f)); }
__device__ __forceinline__ float softplus_f(float x){ return (x > 20.f) ? x : log1pf(__expf(x)); }

// ---------------------------------------------------------------------------
// Patch embedding: h[bv*1024+n, d] = sum_p x[bv,p,n]*Wp[d,p] + bp[d]
__global__ __launch_bounds__(256) void patch_embed(
    const float* __restrict__ x, const float* __restrict__ Wp,
    const float* __restrict__ bp, float* __restrict__ h)
{
    int bv = blockIdx.x, n0 = blockIdx.y * 64;
    __shared__ float xs[PLEN][64];
    __shared__ float ws[PLEN][DM];
    __shared__ float bs[DM];
    int tid = threadIdx.x;
    {
        int c = tid & 63, r0 = tid >> 6;
        for (int p = r0; p < PLEN; p += 4)
            xs[p][c] = x[bv*(PLEN*TSEQ) + p*TSEQ + n0 + c];
    }
    for (int i = tid; i < DM*PLEN; i += 256) {
        int d = i >> 4, p = i & 15;
        ws[p][d] = Wp[i];
    }
    if (tid < DM) bs[tid] = bp[tid];
    __syncthreads();
    int tm = tid & 15;
    int tn = tid >> 4;
    float acc[4][8];
#pragma unroll
    for (int i=0;i<4;i++)
#pragma unroll
        for (int j=0;j<8;j++) acc[i][j] = bs[tn*8+j];
#pragma unroll
    for (int p=0;p<PLEN;p++) {
        float4 a = *(const float4*)&xs[p][tm*4];
        float4 w0 = *(const float4*)&ws[p][tn*8];
        float4 w1 = *(const float4*)&ws[p][tn*8+4];
        const float* ap = (const float*)&a;
        const float* wp0 = (const float*)&w0;
        const float* wp1 = (const float*)&w1;
#pragma unroll
        for (int i=0;i<4;i++){
#pragma unroll
            for (int j=0;j<4;j++){
                acc[i][j]   += ap[i]*wp0[j];
                acc[i][j+4] += ap[i]*wp1[j];
            }
        }
    }
#pragma unroll
    for (int i=0;i<4;i++){
        size_t row = (size_t)(bv*TSEQ + n0 + tm*4 + i)*DM + tn*8;
        *(float4*)&h[row]   = make_float4(acc[i][0],acc[i][1],acc[i][2],acc[i][3]);
        *(float4*)&h[row+4] = make_float4(acc[i][4],acc[i][5],acc[i][6],acc[i][7]);
    }
}

// ---------------------------------------------------------------------------
// Generic tiled GEMM: C[M,N] = A[M,K] @ W[N,K]^T (+bias/act)
// BM=BN=64, BK=16, 256 threads, 4x4 per thread.
template<int EPI>
__global__ __launch_bounds__(256) void gemm64(
    const float* __restrict__ A, const float* __restrict__ W,
    const float* __restrict__ bias, float* __restrict__ C,
    int M, int N, int K)
{
    int m0 = blockIdx.x * 64;
    int n0 = blockIdx.y * 64;
    __shared__ float As[16][64];
    __shared__ float Ws[16][64];
    int tid = threadIdx.x;
    int lr = tid >> 2;          // 0..63
    int lk = (tid & 3) * 4;     // 0,4,8,12
    int tm = tid & 15, tn = tid >> 4;
    float acc[4][4] = {{0.f}};
    for (int k0 = 0; k0 < K; k0 += 16) {
        float4 av = *(const float4*)&A[(size_t)(m0+lr)*K + k0 + lk];
        float4 wv = make_float4(0.f,0.f,0.f,0.f);
        if (n0 + lr < N) wv = *(const float4*)&W[(size_t)(n0+lr)*K + k0 + lk];
        As[lk+0][lr]=av.x; As[lk+1][lr]=av.y; As[lk+2][lr]=av.z; As[lk+3][lr]=av.w;
        Ws[lk+0][lr]=wv.x; Ws[lk+1][lr]=wv.y; Ws[lk+2][lr]=wv.z; Ws[lk+3][lr]=wv.w;
        __syncthreads();
#pragma unroll
        for (int k=0;k<16;k++){
            float4 a = *(const float4*)&As[k][tm*4];
            float4 b = *(const float4*)&Ws[k][tn*4];
            acc[0][0]+=a.x*b.x; acc[0][1]+=a.x*b.y; acc[0][2]+=a.x*b.z; acc[0][3]+=a.x*b.w;
            acc[1][0]+=a.y*b.x; acc[1][1]+=a.y*b.y; acc[1][2]+=a.y*b.z; acc[1][3]+=a.y*b.w;
            acc[2][0]+=a.z*b.x; acc[2][1]+=a.z*b.y; acc[2][2]+=a.z*b.z; acc[2][3]+=a.z*b.w;
            acc[3][0]+=a.w*b.x; acc[3][1]+=a.w*b.y; acc[3][2]+=a.w*b.z; acc[3][3]+=a.w*b.w;
        }
        __syncthreads();
    }
    if (EPI == EPI_XDBL) {
        // write row-major x_dbl [M, 40]; only cols < 40 valid
        if (tn*4 < XDW) {
#pragma unroll
            for (int i=0;i<4;i++){
                int m = m0 + tm*4 + i;
                *(float4*)&C[(size_t)m*XDW + tn*4] =
                    make_float4(acc[i][0],acc[i][1],acc[i][2],acc[i][3]);
            }
        }
    } else {
#pragma unroll
        for (int i=0;i<4;i++){
            int m = m0 + tm*4 + i;
            float4 v = make_float4(acc[i][0],acc[i][1],acc[i][2],acc[i][3]);
            if (EPI == EPI_BIAS || EPI == EPI_GELU) {
                int n = n0 + tn*4;
                v.x += bias[n]; v.y += bias[n+1]; v.z += bias[n+2]; v.w += bias[n+3];
            }
            if (EPI == EPI_GELU) {
                v.x = gelu_f(v.x); v.y = gelu_f(v.y); v.z = gelu_f(v.z); v.w = gelu_f(v.w);
            }
            *(float4*)&C[(size_t)m*N + n0 + tn*4] = v;
        }
    }
}

// ---------------------------------------------------------------------------
// Causal depthwise conv (width 4) + bias + SiLU, row-major output only.
// grid (32 b, 4 ctiles, 16 ttiles), block 256
__global__ __launch_bounds__(256) void conv_silu(
    const float* __restrict__ xz, const float* __restrict__ cw,
    const float* __restrict__ cb, float* __restrict__ xcR)
{
    int b = blockIdx.x, c0 = blockIdx.y*64, t0 = blockIdx.z*64;
    __shared__ float xin_s[67][64];
    __shared__ float cws[64][5];
    __shared__ float cbs[64];
    int tid = threadIdx.x;
    { int c = tid >> 2, k = tid & 3; cws[c][k] = cw[(c0+c)*4 + k]; }
    if (tid < 64) cbs[tid] = cb[c0+tid];
    {
        int c = tid & 63, r0 = tid >> 6;
        for (int r = r0; r < 67; r += 4) {
            int t = t0 - 3 + r;
            xin_s[r][c] = (t >= 0) ? xz[(size_t)(b*TSEQ + t)*(2*DI) + c0 + c] : 0.f;
        }
    }
    __syncthreads();
#pragma unroll
    for (int p = 0; p < 16; p++) {
        int idx = p*256 + tid;
        int tl = idx >> 6, cl = idx & 63;
        float v = cbs[cl];
#pragma unroll
        for (int k=0;k<4;k++) v += cws[cl][k]*xin_s[tl+k][cl];
        xcR[(size_t)(b*TSEQ + t0 + tl)*DI + c0 + cl] = silu_f(v);
    }
}

// ---------------------------------------------------------------------------
// Chunked selective scan, pass 1: per (b, chunk, d) compute local end-state
// (h with h_start=0) and sum of delta over the chunk. Fuses dt_proj+softplus.
// grid (32 b, 16 chunks), block 256 (thread = d)
__global__ __launch_bounds__(256) void scan_pass1(
    const float* __restrict__ x_dbl, const float* __restrict__ xcR,
    const float* __restrict__ dtw, const float* __restrict__ dtb,
    const float* __restrict__ Alog,
    float* __restrict__ hloc, float* __restrict__ sumdelta)
{
    int b = blockIdx.x, c = blockIdx.y;
    int d = threadIdx.x;
    __shared__ __align__(16) float dts[CSZ][8];
    __shared__ __align__(16) float Bs[CSZ][16];
    int mbase = b*TSEQ + c*CSZ;
    for (int i = d; i < CSZ*8; i += 256) {
        int t = i >> 3, k = i & 7;
        dts[t][k] = x_dbl[(size_t)(mbase+t)*XDW + k];
    }
    for (int i = d; i < CSZ*16; i += 256) {
        int t = i >> 4, s = i & 15;
        Bs[t][s] = x_dbl[(size_t)(mbase+t)*XDW + DTR + s];
    }
    float A[16], h[16];
#pragma unroll
    for (int s=0;s<16;s++){ A[s] = -__expf(Alog[d*16+s]); h[s] = 0.f; }
    float w[8];
#pragma unroll
    for (int k=0;k<8;k++) w[k] = dtw[d*8+k];
    float bias = dtb[d];
    float sd = 0.f;
    __syncthreads();
#pragma unroll 4
    for (int t=0;t<CSZ;t++){
        float u = xcR[(size_t)(mbase+t)*DI + d];
        float acc = bias;
#pragma unroll
        for (int k=0;k<8;k++) acc += dts[t][k]*w[k];
        float dlt = softplus_f(acc);
        sd += dlt;
        float du = dlt*u;
        const float* Bv = &Bs[t][0];
#pragma unroll
        for (int s=0;s<16;s++)
            h[s] = __expf(dlt*A[s])*h[s] + du*Bv[s];
    }
    float* hp = &hloc[((size_t)((b*NCH + c)*256 + d))*16];
#pragma unroll
    for (int s=0;s<16;s+=4)
        *(float4*)&hp[s] = make_float4(h[s],h[s+1],h[s+2],h[s+3]);
    sumdelta[(b*NCH + c)*256 + d] = sd;
}

// ---------------------------------------------------------------------------
// Chunked selective scan, pass 2: reconstruct h_start from earlier chunks,
// replay recurrence, emit y = (scan + u*D) * silu(z), row-major.
// grid (32 b, 16 chunks), block 256 (thread = d)
__global__ __launch_bounds__(256) void scan_pass2(
    const float* __restrict__ x_dbl, const float* __restrict__ xcR,
    const float* __restrict__ xz,
    const float* __restrict__ dtw, const float* __restrict__ dtb,
    const float* __restrict__ Alog, const float* __restrict__ Dp,
    const float* __restrict__ hloc, const float* __restrict__ sumdelta,
    float* __restrict__ yR)
{
    int b = blockIdx.x, c = blockIdx.y;
    int d = threadIdx.x;
    __shared__ __align__(16) float dts[CSZ][8];
    __shared__ __align__(16) float Bs[CSZ][16];
    __shared__ __align__(16) float Cs[CSZ][16];
    int mbase = b*TSEQ + c*CSZ;
    for (int i = d; i < CSZ*8; i += 256) {
        int t = i >> 3, k = i & 7;
        dts[t][k] = x_dbl[(size_t)(mbase+t)*XDW + k];
    }
    for (int i = d; i < CSZ*16; i += 256) {
        int t = i >> 4, s = i & 15;
        Bs[t][s] = x_dbl[(size_t)(mbase+t)*XDW + DTR + s];
        Cs[t][s] = x_dbl[(size_t)(mbase+t)*XDW + DTR + DS + s];
    }
    float A[16], h[16];
#pragma unroll
    for (int s=0;s<16;s++){ A[s] = -__expf(Alog[d*16+s]); h[s] = 0.f; }
    float w[8];
#pragma unroll
    for (int k=0;k<8;k++) w[k] = dtw[d*8+k];
    float bias = dtb[d];
    float Dd = Dp[d];
    // combine earlier chunks: h_start
    for (int cp = 0; cp < c; cp++){
        float sdp = sumdelta[(b*NCH + cp)*256 + d];
        const float* hl = &hloc[((size_t)((b*NCH + cp)*256 + d))*16];
        float4 h0 = *(const float4*)&hl[0];
        float4 h1 = *(const float4*)&hl[4];
        float4 h2 = *(const float4*)&hl[8];
        float4 h3 = *(const float4*)&hl[12];
        const float* hv = (const float*)&h0;
        float hls[16] = {h0.x,h0.y,h0.z,h0.w,h1.x,h1.y,h1.z,h1.w,
                         h2.x,h2.y,h2.z,h2.w,h3.x,h3.y,h3.z,h3.w};
        (void)hv;
#pragma unroll
        for (int s=0;s<16;s++)
            h[s] = __expf(sdp*A[s])*h[s] + hls[s];
    }
    __syncthreads();
#pragma unroll 4
    for (int t=0;t<CSZ;t++){
        int m = mbase + t;
        float u = xcR[(size_t)m*DI + d];
        float acc = bias;
#pragma unroll
        for (int k=0;k<8;k++) acc += dts[t][k]*w[k];
        float dlt = softplus_f(acc);
        float du = dlt*u;
        const float* Bv = &Bs[t][0];
        const float* Cv = &Cs[t][0];
        float y = 0.f;
#pragma unroll
        for (int s=0;s<16;s++){
            h[s] = __expf(dlt*A[s])*h[s] + du*Bv[s];
            y += h[s]*Cv[s];
        }
        float z = xz[(size_t)m*(2*DI) + DI + d];
        yR[(size_t)m*DI + d] = (y + u*Dd) * silu_f(z);
    }
}

// ---------------------------------------------------------------------------
// Final transpose: out[bv, d, n] = h[bv*1024+n, d]
__global__ __launch_bounds__(256) void final_transpose(
    const float* __restrict__ h, float* __restrict__ out)
{
    int n0 = blockIdx.x*32, d0 = blockIdx.y*32, bv = blockIdx.z;
    __shared__ float ts[32][33];
    int tid = threadIdx.x;
    int c = tid & 31, r0 = tid >> 5;
    for (int r = r0; r < 32; r += 8)
        ts[r][c] = h[(size_t)(bv*TSEQ + n0 + r)*DM + d0 + c];
    __syncthreads();
    for (int r = r0; r < 32; r += 8)
        out[(size_t)(bv*DM + d0 + r)*TSEQ + n0 + c] = ts[c][r];
}

// ---------------------------------------------------------------------------
extern "C" void kernel_launch(void* const* d_in, const int* in_sizes, int n_in,
                              void* d_out, int out_size, void* d_ws, size_t ws_size,
                              hipStream_t stream)
{
    const float* x     = (const float*)d_in[0];
    const float* Wp    = (const float*)d_in[1];
    const float* Wpb   = (const float*)d_in[2];
    const float* inW   = (const float*)d_in[3];
    const float* convW = (const float*)d_in[4];
    const float* convB = (const float*)d_in[5];
    const float* xpW   = (const float*)d_in[6];
    const float* dtW   = (const float*)d_in[7];
    const float* dtB   = (const float*)d_in[8];
    const float* Alog  = (const float*)d_in[9];
    const float* Dp    = (const float*)d_in[10];
    const float* outW  = (const float*)d_in[11];
    const float* l1W   = (const float*)d_in[12];
    const float* l1B   = (const float*)d_in[13];
    const float* l2W   = (const float*)d_in[14];
    const float* l2B   = (const float*)d_in[15];
    float* out = (float*)d_out;

    float* ws = (float*)d_ws;
    float* h     = ws;                          // 32768*128   = 16.8 MB
    float* xz    = h     + (size_t)MTOK*DM;     // 32768*512   = 67 MB
    float* xcR   = xz    + (size_t)MTOK*2*DI;   // 32768*256   = 33.5 MB
    float* x_dbl = xcR   + (size_t)MTOK*DI;     // 32768*40    = 5.2 MB
    float* yR    = x_dbl + (size_t)MTOK*XDW;    // 32768*256   = 33.5 MB
    float* hloc  = yR    + (size_t)MTOK*DI;     // 32*16*256*16= 8.4 MB
    float* sdel  = hloc  + (size_t)BSEQ*NCH*DI*DS; // 131072   = 0.5 MB
    float* ffn   = xz;   // alias: xz dead after scan_pass2 (z consumed)

    patch_embed<<<dim3(32,16), 256, 0, stream>>>(x, Wp, Wpb, h);

    for (int L = 0; L < L_LAYERS; L++) {
        const float* inW_l   = inW   + (size_t)L*2*DI*DM;
        const float* convW_l = convW + (size_t)L*DI*4;
        const float* convB_l = convB + (size_t)L*DI;
        const float* xpW_l   = xpW   + (size_t)L*XDW*DI;
        const float* dtW_l   = dtW   + (size_t)L*DI*DTR;
        const float* dtB_l   = dtB   + (size_t)L*DI;
        const float* Alog_l  = Alog  + (size_t)L*DI*DS;
        const float* Dp_l    = Dp    + (size_t)L*DI;
        const float* outW_l  = outW  + (size_t)L*DM*DI;
        const float* l1W_l   = l1W   + (size_t)L*DFF*DM;
        const float* l1B_l   = l1B   + (size_t)L*DFF;
        const float* l2W_l   = l2W   + (size_t)L*DM*DFF;
        const float* l2B_l   = l2B   + (size_t)L*DM;

        // xz = h @ in_w^T : (32768 x 512), K=128
        gemm64<EPI_NONE><<<dim3(MTOK/64, (2*DI)/64), 256, 0, stream>>>(
            h, inW_l, nullptr, xz, MTOK, 2*DI, DM);
        // conv + silu (row-major)
        conv_silu<<<dim3(BSEQ, DI/64, TSEQ/64), 256, 0, stream>>>(
            xz, convW_l, convB_l, xcR);
        // x_dbl = xc @ xp_w^T : (32768 x 40), K=256, row-major out
        gemm64<EPI_XDBL><<<dim3(MTOK/64, 1), 256, 0, stream>>>(
            xcR, xpW_l, nullptr, x_dbl, MTOK, XDW, DI);
        // chunked scan (fused dt_proj + softplus + u*D + silu(z) gate)
        scan_pass1<<<dim3(BSEQ, NCH), 256, 0, stream>>>(
            x_dbl, xcR, dtW_l, dtB_l, Alog_l, hloc, sdel);
        scan_pass2<<<dim3(BSEQ, NCH), 256, 0, stream>>>(
            x_dbl, xcR, xz, dtW_l, dtB_l, Alog_l, Dp_l, hloc, sdel, yR);
        // h = y @ out_w^T : (32768 x 128), K=256
        gemm64<EPI_NONE><<<dim3(MTOK/64, DM/64), 256, 0, stream>>>(
            yR, outW_l, nullptr, h, MTOK, DM, DI);
        // ffn = gelu(h @ l1^T + b1) : (32768 x 256), K=128
        gemm64<EPI_GELU><<<dim3(MTOK/64, DFF/64), 256, 0, stream>>>(
            h, l1W_l, l1B_l, ffn, MTOK, DFF, DM);
        // h = ffn @ l2^T + b2 : (32768 x 128), K=256
        gemm64<EPI_BIAS><<<dim3(MTOK/64, DM/64), 256, 0, stream>>>(
            ffn, l2W_l, l2B_l, h, MTOK, DM, DFF);
    }

    final_transpose<<<dim3(TSEQ/32, DM/32, BSEQ), 256, 0, stream>>>(h, out);
}